// Round 1
// baseline (173.135 us; speedup 1.0000x reference)
//
#include <hip/hip_runtime.h>
#include <hip/hip_bf16.h>
#include <math.h>

#define En   8
#define Bn   4096
#define Ln   512
#define K1n  1024   // 2L
#define H1n  1024
#define H2n  512
#define Cn   40
#define NP3  48     // layer-3 padded N

typedef unsigned short u16;
typedef __attribute__((ext_vector_type(8))) short bf16x8;
typedef __attribute__((ext_vector_type(4))) float f32x4;

// f32 -> bf16 (RNE), finite inputs
__device__ __forceinline__ u16 f2b(float f) {
    union { float f; unsigned int u; } v; v.f = f;
    unsigned int r = v.u + 0x7FFF + ((v.u >> 16) & 1);
    return (u16)(r >> 16);
}

// async global->LDS 16B copy; LDS dest must be wave-uniform base + lane*16.
__device__ __forceinline__ void g2l16(const void* g, void* l) {
    __builtin_amdgcn_global_load_lds(
        (const __attribute__((address_space(1))) unsigned int*)(unsigned long long)g,
        (__attribute__((address_space(3))) unsigned int*)(unsigned int)(unsigned long long)l,
        16, 0, 0);
}

// 64x64 f32->bf16 transpose tile via LDS
__device__ __forceinline__ void wtrans64(
    const float* __restrict__ Wsrc, u16* __restrict__ Wdst,
    int K, int N, int k0, int n0, int tid, float* sm /* [64][65] */)
{
    #pragma unroll
    for (int s = 0; s < 4; s++) {
        int idx = tid + s * 256;
        int kk = idx >> 4, c4 = (idx & 15) * 4;
        float4 v = *(const float4*)&Wsrc[(size_t)(k0 + kk) * N + n0 + c4];
        float* row = sm + kk * 65 + c4;
        row[0] = v.x; row[1] = v.y; row[2] = v.z; row[3] = v.w;
    }
    __syncthreads();
    #pragma unroll
    for (int s = 0; s < 4; s++) {
        int idx = tid + s * 256;
        int nn = idx >> 4, kc = (idx & 15) * 4;
        ushort4 o = make_ushort4(f2b(sm[(kc + 0) * 65 + nn]), f2b(sm[(kc + 1) * 65 + nn]),
                                 f2b(sm[(kc + 2) * 65 + nn]), f2b(sm[(kc + 3) * 65 + nn]));
        *(ushort4*)&Wdst[(size_t)(n0 + nn) * K + k0 + kc] = o;
    }
}

// ---------------------------------------------------------------------------
// prep1: only L1's dependencies.  0: route; 1..256: Xb; 257..2304: W1t.
// ---------------------------------------------------------------------------
#define P1_TOT (1 + 256 + 2048)

__global__ __launch_bounds__(256) void prep1_kernel(
    const float* __restrict__ xs, const float* __restrict__ xp,
    const float* __restrict__ W1, const int* __restrict__ label,
    int* __restrict__ meta, int* __restrict__ perm,
    u16* __restrict__ Xb, u16* __restrict__ W1t)
{
    __shared__ __align__(16) float sm[64 * 65];
    const int bid = blockIdx.x;
    const int tid = threadIdx.x;

    if (bid == 0) {
        int* cnt = (int*)sm;
        int* off = cnt + En;
        if (tid < En) cnt[tid] = 0;
        __syncthreads();
        for (int b = tid; b < Bn; b += 256) atomicAdd(&cnt[label[b]], 1);
        __syncthreads();
        if (tid == 0) {
            int run = 0;
            for (int e = 0; e < En; e++) { off[e] = run; run += cnt[e]; }
            off[En] = run;
        }
        __syncthreads();
        if (tid < En) cnt[tid] = off[tid];
        __syncthreads();
        for (int b = tid; b < Bn; b += 256) {
            int e = label[b];
            perm[atomicAdd(&cnt[e], 1)] = b;
        }
        if (tid <= En) meta[tid] = off[tid];
    } else if (bid < 257) {
        int r0 = (bid - 1) * 16;
        #pragma unroll 4
        for (int s = 0; s < 16; s++) {
            int r = r0 + s;
            int k = tid * 4;
            const float* src = (k < Ln) ? (xp + (size_t)r * Ln + k)
                                        : (xs + (size_t)r * Ln + (k - Ln));
            float4 v = *(const float4*)src;
            *(ushort4*)&Xb[(size_t)r * K1n + k] =
                make_ushort4(f2b(v.x), f2b(v.y), f2b(v.z), f2b(v.w));
        }
    } else {
        int b = bid - 257;
        int e = b >> 8, rem = b & 255;
        int k0 = (rem >> 4) * 64, n0 = (rem & 15) * 64;
        wtrans64(W1 + (size_t)e * K1n * H1n, W1t + (size_t)e * H1n * K1n,
                 K1n, H1n, k0, n0, tid, sm);
    }
}

// ---------------------------------------------------------------------------
// Grouped bf16 MFMA GEMM, m97-class structure:
//   TM x TN tile, BK=32, 4 waves each owning a (TM/2)x(TN/2) quadrant,
//   double-buffered async global_load_lds (2 stages, A+B), per-K-step per
//   wave: (TM+TN)/16 ds_read_b128 + (TM*TN)/1024 MFMA.
// LDS chunk swizzle (BK=32, 4 x 16B chunks/row): chunk c of row r stored at
//   slot c ^ ((r>>1)&3)  -> ds_read_b128 lands 2 lanes/bank-quad (free).
// PREP2 (L1 instance): tail blocks run W2t/W3t/out-init jobs.
// FUSE3 (L2 instance): fused layer-3 k-split epilogue, atomicAdd into outf.
// ---------------------------------------------------------------------------
template <int K, int N, int TM, int TN, bool GATHER, bool FUSE3, bool PREP2>
__global__ __launch_bounds__(256) void mfma_gemm(
    const u16* __restrict__ A, const u16* __restrict__ Wt,
    const float* __restrict__ bias, const int* __restrict__ meta,
    const int* __restrict__ perm, u16* __restrict__ outb,
    const u16* __restrict__ Wt3, float* __restrict__ outf,
    const float* __restrict__ W2f, const float* __restrict__ W3f,
    const float* __restrict__ b3v, const int* __restrict__ labelv,
    u16* __restrict__ W2t_o, u16* __restrict__ W3t_o)
{
    constexpr int BK    = 32;
    constexpr int T     = K / BK;
    constexpr int NTC   = N / TN;
    constexpr int NTRk  = Bn / TM + En;      // max row tiles
    constexpr int ASLOT = TM * 4;            // 16B chunks per A stage
    constexpr int BSLOT = TN * 4;
    constexpr int STAGE = ASLOT + BSLOT;     // chunks per stage
    constexpr int HSTR  = TN + 8;            // fused-L3 H tile stride (u16)
    constexpr int SMST  = 2 * STAGE * 8;     // staging u16 count
    constexpr int SMU16 = (FUSE3 && (TM * HSTR) > SMST) ? (TM * HSTR) : SMST;
    __shared__ __align__(16) u16 SM[SMU16];

    const int tid = threadIdx.x;
    const int bx = blockIdx.x;

    if (PREP2 && bx >= NTRk * NTC) {
        int jb = bx - NTRk * NTC;
        if (jb < 1024) {               // W2 transpose
            int e = jb >> 7, rem = jb & 127;
            int k0 = (rem >> 3) * 64, n0 = (rem & 7) * 64;
            wtrans64(W2f + (size_t)e * H1n * H2n, W2t_o + (size_t)e * H2n * H1n,
                     H1n, H2n, k0, n0, tid, (float*)SM);
        } else if (jb < 1024 + 128) {  // W3 transpose+pad
            int b = jb - 1024;
            int e = b >> 4, k0 = (b & 15) * 32;
            const float* src = W3f + (size_t)e * H2n * Cn;
            u16* dst = W3t_o + (size_t)e * NP3 * H2n;
            float* t = (float*)SM;     // [32][41]
            #pragma unroll
            for (int s = 0; s < 5; s++) {
                int idx = tid + s * 256;
                int kk = idx / Cn, nn = idx - kk * Cn;
                if (kk < 32) t[kk * 41 + nn] = src[(size_t)(k0 + kk) * Cn + nn];
            }
            __syncthreads();
            #pragma unroll
            for (int s = 0; s < 6; s++) {
                int idx = tid + s * 256;
                int nn = idx >> 5, kk = idx & 31;
                float v = (nn < Cn) ? t[kk * 41 + nn] : 0.f;
                dst[(size_t)nn * H2n + k0 + kk] = f2b(v);
            }
        } else {                       // out bias pre-init
            int b = jb - (1024 + 128);
            int r0 = b * 64;
            #pragma unroll
            for (int s = 0; s < 10; s++) {
                int idx = tid + s * 256;
                int r = r0 + idx / Cn;
                int c = idx - (idx / Cn) * Cn;
                outf[(size_t)r * Cn + c] = b3v[labelv[r] * Cn + c];
            }
        }
        return;
    }

    const int rt = bx % NTRk;
    const int col0 = (bx / NTRk) * TN;

    int expert = -1, row0 = 0, rowmax = 0, acc_t = 0;
    int prev = meta[0];
    #pragma unroll
    for (int e = 0; e < En; e++) {
        int nxt = meta[e + 1];
        int c = nxt - prev;
        int t = (c + TM - 1) / TM;
        if (expert < 0 && rt < acc_t + t) {
            expert = e; row0 = prev + (rt - acc_t) * TM; rowmax = nxt - 1;
        }
        acc_t += t; prev = nxt;
    }
    if (expert < 0) return;

    const u16* Wexp = Wt + (size_t)expert * N * K;

    const int lane = tid & 63;
    const int wid = tid >> 6;
    const int wm = (wid & 1) * (TM / 2);
    const int wn = (wid >> 1) * (TN / 2);
    const int l15 = lane & 15;
    const int lq = lane >> 4;

    // staging: slot idx -> row rl = idx>>2, slot c = idx&3 holds global
    // k-chunk c^((rl>>1)&3); LDS off = 16B * (stagebase + region + idx).
    constexpr int ALOAD = ASLOT / 256;
    constexpr int BLOAD = BSLOT / 256;
    const u16* aptr[ALOAD]; int aoff[ALOAD];
    const u16* bptr[BLOAD]; int boff[BLOAD];
    #pragma unroll
    for (int s = 0; s < ALOAD; s++) {
        int idx = tid + s * 256;
        int rl = idx >> 2, c = idx & 3;
        int kq = c ^ ((rl >> 1) & 3);
        int rg = row0 + rl; if (rg > rowmax) rg = rowmax;
        if (GATHER) rg = perm[rg];
        aptr[s] = A + (size_t)rg * K + kq * 8;
        aoff[s] = idx * 8;
    }
    #pragma unroll
    for (int s = 0; s < BLOAD; s++) {
        int idx = tid + s * 256;
        int rl = idx >> 2, c = idx & 3;
        int kq = c ^ ((rl >> 1) & 3);
        bptr[s] = Wexp + (size_t)(col0 + rl) * K + kq * 8;
        boff[s] = ASLOT * 8 + idx * 8;
    }

    constexpr int MI = TM / 32;    // 16-row fragments per wave (M)
    constexpr int NJ = TN / 32;    // 16-col fragments per wave (N)
    f32x4 acc[MI][NJ];
    #pragma unroll
    for (int i = 0; i < MI; i++)
        #pragma unroll
        for (int j = 0; j < NJ; j++) acc[i][j] = (f32x4){0.f, 0.f, 0.f, 0.f};

    // prologue: tile 0 -> stage 0
    #pragma unroll
    for (int s = 0; s < ALOAD; s++) g2l16(aptr[s], &SM[aoff[s]]);
    #pragma unroll
    for (int s = 0; s < BLOAD; s++) g2l16(bptr[s], &SM[boff[s]]);

    // read-side swizzled chunk offset (u16): row bits 1..2 == l15 bits 1..2
    const int cp = (lq ^ ((l15 >> 1) & 3)) * 8;

    for (int t = 0; t < T; t++) {
        __syncthreads();
        const u16* As = &SM[(t & 1) * (STAGE * 8)];
        const u16* Bs = As + ASLOT * 8;
        if (t + 1 < T) {
            int base = ((t + 1) & 1) * (STAGE * 8);
            int ko = (t + 1) * BK;
            #pragma unroll
            for (int s = 0; s < ALOAD; s++) g2l16(aptr[s] + ko, &SM[base + aoff[s]]);
            #pragma unroll
            for (int s = 0; s < BLOAD; s++) g2l16(bptr[s] + ko, &SM[base + boff[s]]);
        }
        bf16x8 af[MI], bf[NJ];
        #pragma unroll
        for (int i = 0; i < MI; i++)
            af[i] = *(const bf16x8*)&As[(wm + i * 16 + l15) * BK + cp];
        #pragma unroll
        for (int j = 0; j < NJ; j++)
            bf[j] = *(const bf16x8*)&Bs[(wn + j * 16 + l15) * BK + cp];
        #pragma unroll
        for (int i = 0; i < MI; i++)
            #pragma unroll
            for (int j = 0; j < NJ; j++)
                acc[i][j] = __builtin_amdgcn_mfma_f32_16x16x32_bf16(
                    af[i], bf[j], acc[i][j], 0, 0, 0);
    }

    if (!FUSE3) {
        // bias + ELU -> global bf16.  C/D: col=l15, row=lq*4+reg
        #pragma unroll
        for (int i = 0; i < MI; i++) {
            #pragma unroll
            for (int j = 0; j < NJ; j++) {
                int col = col0 + wn + j * 16 + l15;
                float bv = bias[expert * N + col];
                #pragma unroll
                for (int r = 0; r < 4; r++) {
                    int grow = row0 + wm + i * 16 + lq * 4 + r;
                    if (grow <= rowmax) {
                        float v = acc[i][j][r] + bv;
                        v = (v > 0.f) ? v : (expf(v) - 1.f);
                        outb[(size_t)grow * N + col] = f2b(v);
                    }
                }
            }
        }
    } else {
        // fused layer 3: k-split over this block's TN h-cols
        __syncthreads();
        u16* H = &SM[0];   // [TM][HSTR] bf16
        #pragma unroll
        for (int i = 0; i < MI; i++) {
            #pragma unroll
            for (int j = 0; j < NJ; j++) {
                int col = wn + j * 16 + l15;
                float bv = bias[expert * N + col0 + col];
                #pragma unroll
                for (int r = 0; r < 4; r++) {
                    float v = acc[i][j][r] + bv;
                    v = (v > 0.f) ? v : (expf(v) - 1.f);
                    H[(wm + i * 16 + lq * 4 + r) * HSTR + col] = f2b(v);
                }
            }
        }
        __syncthreads();
        constexpr int RI = TM / 64;         // 16-row frags per wave (TM/4 rows)
        constexpr int KC = TN / 32;         // k-chunks over this block's h-cols
        const int rh = wid * (TM / 4);
        f32x4 a3[RI][3];
        #pragma unroll
        for (int ri = 0; ri < RI; ri++)
            #pragma unroll
            for (int j = 0; j < 3; j++) a3[ri][j] = (f32x4){0.f, 0.f, 0.f, 0.f};
        #pragma unroll
        for (int ki = 0; ki < KC; ki++) {
            bf16x8 ha[RI];
            #pragma unroll
            for (int ri = 0; ri < RI; ri++)
                ha[ri] = *(const bf16x8*)&H[(rh + ri * 16 + l15) * HSTR + ki * 32 + lq * 8];
            #pragma unroll
            for (int j = 0; j < 3; j++) {
                bf16x8 wb = *(const bf16x8*)
                    &Wt3[((size_t)expert * NP3 + j * 16 + l15) * H2n + col0 + ki * 32 + lq * 8];
                #pragma unroll
                for (int ri = 0; ri < RI; ri++)
                    a3[ri][j] = __builtin_amdgcn_mfma_f32_16x16x32_bf16(
                        ha[ri], wb, a3[ri][j], 0, 0, 0);
            }
        }
        #pragma unroll
        for (int j = 0; j < 3; j++) {
            int col = j * 16 + l15;
            if (col < Cn) {
                #pragma unroll
                for (int ri = 0; ri < RI; ri++) {
                    #pragma unroll
                    for (int r = 0; r < 4; r++) {
                        int grow = row0 + rh + ri * 16 + lq * 4 + r;
                        if (grow <= rowmax)
                            atomicAdd(&outf[(size_t)perm[grow] * Cn + col], a3[ri][j][r]);
                    }
                }
            }
        }
    }
}

// ---------------------------------------------------------------------------
extern "C" void kernel_launch(void* const* d_in, const int* in_sizes, int n_in,
                              void* d_out, int out_size, void* d_ws, size_t ws_size,
                              hipStream_t stream)
{
    const float* xs = (const float*)d_in[0];
    const float* xp = (const float*)d_in[1];
    const float* W1 = (const float*)d_in[2];
    const float* b1 = (const float*)d_in[3];
    const float* W2 = (const float*)d_in[4];
    const float* b2 = (const float*)d_in[5];
    const float* W3 = (const float*)d_in[6];
    const float* b3 = (const float*)d_in[7];
    const int* label = (const int*)d_in[8];
    float* out = (float*)d_out;

    char* ws = (char*)d_ws;
    int* meta = (int*)ws;                                    // 64 B
    int* perm = (int*)(ws + 64);                             // 16 KB
    u16* Xb  = (u16*)(ws + (64 << 10));                      // 8 MB [4096][1024] (orig)
    u16* W1t = (u16*)(ws + (64 << 10) + (8  << 20));         // 16 MB [8][1024][1024]
    u16* W2t = (u16*)(ws + (64 << 10) + (24 << 20));         // 8 MB  [8][512][1024]
    u16* h1b = (u16*)(ws + (64 << 10) + (32 << 20));         // 8 MB  [4096][1024] (sorted)
    u16* W3t = (u16*)(ws + (64 << 10) + (40 << 20));         // 393 KB [8][48][512]

    prep1_kernel<<<P1_TOT, 256, 0, stream>>>(
        xs, xp, W1, label, meta, perm, Xb, W1t);

    // L1 GEMM: 128x128 tiles, (4096/128+8)*8 = 320 blocks + 1216 prep2 jobs
    mfma_gemm<K1n, H1n, 128, 128, true, false, true><<<320 + 1216, 256, 0, stream>>>(
        Xb, W1t, b1, meta, perm, h1b, nullptr, out,
        W2, W3, b3, label, W2t, W3t);

    // L2 + fused L3: 128x64 tiles, (4096/128+8)*8 = 320 blocks
    mfma_gemm<H1n, H2n, 128, 64, false, true, false><<<320, 256, 0, stream>>>(
        h1b, W2t, b2, meta, perm, nullptr, W3t, out,
        nullptr, nullptr, nullptr, nullptr, nullptr, nullptr);
}

// Round 2
// 171.322 us; speedup vs baseline: 1.0106x; 1.0106x over previous
//
#include <hip/hip_runtime.h>
#include <hip/hip_bf16.h>
#include <math.h>

#define En   8
#define Bn   4096
#define Ln   512
#define K1n  1024   // 2L
#define H1n  1024
#define H2n  512
#define Cn   40
#define NP3  48     // layer-3 padded N

typedef unsigned short u16;
typedef __attribute__((ext_vector_type(8))) short bf16x8;
typedef __attribute__((ext_vector_type(4))) float f32x4;

// f32 -> bf16 (RNE), finite inputs
__device__ __forceinline__ u16 f2b(float f) {
    union { float f; unsigned int u; } v; v.f = f;
    unsigned int r = v.u + 0x7FFF + ((v.u >> 16) & 1);
    return (u16)(r >> 16);
}

// async global->LDS 16B copy; LDS dest must be wave-uniform base + lane*16.
__device__ __forceinline__ void g2l16(const void* g, void* l) {
    __builtin_amdgcn_global_load_lds(
        (const __attribute__((address_space(1))) unsigned int*)(unsigned long long)g,
        (__attribute__((address_space(3))) unsigned int*)(unsigned int)(unsigned long long)l,
        16, 0, 0);
}

// 64x64 f32->bf16 transpose tile via LDS
__device__ __forceinline__ void wtrans64(
    const float* __restrict__ Wsrc, u16* __restrict__ Wdst,
    int K, int N, int k0, int n0, int tid, float* sm /* [64][65] */)
{
    #pragma unroll
    for (int s = 0; s < 4; s++) {
        int idx = tid + s * 256;
        int kk = idx >> 4, c4 = (idx & 15) * 4;
        float4 v = *(const float4*)&Wsrc[(size_t)(k0 + kk) * N + n0 + c4];
        float* row = sm + kk * 65 + c4;
        row[0] = v.x; row[1] = v.y; row[2] = v.z; row[3] = v.w;
    }
    __syncthreads();
    #pragma unroll
    for (int s = 0; s < 4; s++) {
        int idx = tid + s * 256;
        int nn = idx >> 4, kc = (idx & 15) * 4;
        ushort4 o = make_ushort4(f2b(sm[(kc + 0) * 65 + nn]), f2b(sm[(kc + 1) * 65 + nn]),
                                 f2b(sm[(kc + 2) * 65 + nn]), f2b(sm[(kc + 3) * 65 + nn]));
        *(ushort4*)&Wdst[(size_t)(n0 + nn) * K + k0 + kc] = o;
    }
}

// ---------------------------------------------------------------------------
// prep1: only L1's dependencies.  0: route; 1..256: Xb; 257..2304: W1t.
// ---------------------------------------------------------------------------
#define P1_TOT (1 + 256 + 2048)

__global__ __launch_bounds__(256) void prep1_kernel(
    const float* __restrict__ xs, const float* __restrict__ xp,
    const float* __restrict__ W1, const int* __restrict__ label,
    int* __restrict__ meta, int* __restrict__ perm,
    u16* __restrict__ Xb, u16* __restrict__ W1t)
{
    __shared__ __align__(16) float sm[64 * 65];
    const int bid = blockIdx.x;
    const int tid = threadIdx.x;

    if (bid == 0) {
        int* cnt = (int*)sm;
        int* off = cnt + En;
        if (tid < En) cnt[tid] = 0;
        __syncthreads();
        for (int b = tid; b < Bn; b += 256) atomicAdd(&cnt[label[b]], 1);
        __syncthreads();
        if (tid == 0) {
            int run = 0;
            for (int e = 0; e < En; e++) { off[e] = run; run += cnt[e]; }
            off[En] = run;
        }
        __syncthreads();
        if (tid < En) cnt[tid] = off[tid];
        __syncthreads();
        for (int b = tid; b < Bn; b += 256) {
            int e = label[b];
            perm[atomicAdd(&cnt[e], 1)] = b;
        }
        if (tid <= En) meta[tid] = off[tid];
    } else if (bid < 257) {
        int r0 = (bid - 1) * 16;
        #pragma unroll 4
        for (int s = 0; s < 16; s++) {
            int r = r0 + s;
            int k = tid * 4;
            const float* src = (k < Ln) ? (xp + (size_t)r * Ln + k)
                                        : (xs + (size_t)r * Ln + (k - Ln));
            float4 v = *(const float4*)src;
            *(ushort4*)&Xb[(size_t)r * K1n + k] =
                make_ushort4(f2b(v.x), f2b(v.y), f2b(v.z), f2b(v.w));
        }
    } else {
        int b = bid - 257;
        int e = b >> 8, rem = b & 255;
        int k0 = (rem >> 4) * 64, n0 = (rem & 15) * 64;
        wtrans64(W1 + (size_t)e * K1n * H1n, W1t + (size_t)e * H1n * K1n,
                 K1n, H1n, k0, n0, tid, sm);
    }
}

// ---------------------------------------------------------------------------
// Grouped bf16 MFMA GEMM.
//   TM x TN tile, BK=32, 4 waves each a (TM/2)x(TN/2) quadrant.
//   3-stage LDS ring, counted s_waitcnt vmcnt(LW) + raw s_barrier per K-step
//   (never vmcnt(0) in the main loop -> ~2 iterations of load slack).
//   Barrier sandwich: [asm waitcnt(mem)][s_barrier][asm ""(mem)] so no
//   ds_read / global_load_lds can cross the barrier (race-free 3-stage ring).
// LDS chunk swizzle (BK=32, 4 x 16B chunks/row): chunk c of row r stored at
//   slot c ^ ((r>>1)&3)  -> ds_read_b128 lands 2 lanes/bank-quad (free).
// XCD-aware bijective swizzle on the GEMM block range (NGEMM % 8 == 0).
// PREP2 (L1 instance): tail blocks run W2t/W3t/out-init jobs.
// FUSE3 (L2 instance): fused layer-3 k-split epilogue, atomicAdd into outf.
// ---------------------------------------------------------------------------
template <int K, int N, int TM, int TN, bool GATHER, bool FUSE3, bool PREP2>
__global__ __launch_bounds__(256) void mfma_gemm(
    const u16* __restrict__ A, const u16* __restrict__ Wt,
    const float* __restrict__ bias, const int* __restrict__ meta,
    const int* __restrict__ perm, u16* __restrict__ outb,
    const u16* __restrict__ Wt3, float* __restrict__ outf,
    const float* __restrict__ W2f, const float* __restrict__ W3f,
    const float* __restrict__ b3v, const int* __restrict__ labelv,
    u16* __restrict__ W2t_o, u16* __restrict__ W3t_o)
{
    constexpr int BK    = 32;
    constexpr int T     = K / BK;
    constexpr int NTC   = N / TN;
    constexpr int NTRk  = Bn / TM + En;      // max row tiles
    constexpr int NGEMM = NTRk * NTC;
    constexpr int ASLOT = TM * 4;            // 16B chunks per A stage
    constexpr int BSLOT = TN * 4;
    constexpr int STAGE = ASLOT + BSLOT;     // chunks per stage
    constexpr int ALOAD = ASLOT / 256;       // g2l16 per thread (A)
    constexpr int BLOAD = BSLOT / 256;       // g2l16 per thread (B)
    constexpr int LW    = ALOAD + BLOAD;     // loads/thread/stage
    constexpr int HSTR  = TN + 8;            // fused-L3 H tile stride (u16)
    constexpr int SMST  = 3 * STAGE * 8;     // staging u16 count (3 stages)
    constexpr int SMU16 = (FUSE3 && (TM * HSTR) > SMST) ? (TM * HSTR) : SMST;
    __shared__ __align__(16) u16 SM[SMU16];

    const int tid = threadIdx.x;
    const int bx = blockIdx.x;

    if (PREP2 && bx >= NGEMM) {
        int jb = bx - NGEMM;
        if (jb < 1024) {               // W2 transpose
            int e = jb >> 7, rem = jb & 127;
            int k0 = (rem >> 3) * 64, n0 = (rem & 7) * 64;
            wtrans64(W2f + (size_t)e * H1n * H2n, W2t_o + (size_t)e * H2n * H1n,
                     H1n, H2n, k0, n0, tid, (float*)SM);
        } else if (jb < 1024 + 128) {  // W3 transpose+pad
            int b = jb - 1024;
            int e = b >> 4, k0 = (b & 15) * 32;
            const float* src = W3f + (size_t)e * H2n * Cn;
            u16* dst = W3t_o + (size_t)e * NP3 * H2n;
            float* t = (float*)SM;     // [32][41]
            #pragma unroll
            for (int s = 0; s < 5; s++) {
                int idx = tid + s * 256;
                int kk = idx / Cn, nn = idx - kk * Cn;
                if (kk < 32) t[kk * 41 + nn] = src[(size_t)(k0 + kk) * Cn + nn];
            }
            __syncthreads();
            #pragma unroll
            for (int s = 0; s < 6; s++) {
                int idx = tid + s * 256;
                int nn = idx >> 5, kk = idx & 31;
                float v = (nn < Cn) ? t[kk * 41 + nn] : 0.f;
                dst[(size_t)nn * H2n + k0 + kk] = f2b(v);
            }
        } else {                       // out bias pre-init
            int b = jb - (1024 + 128);
            int r0 = b * 64;
            #pragma unroll
            for (int s = 0; s < 10; s++) {
                int idx = tid + s * 256;
                int r = r0 + idx / Cn;
                int c = idx - (idx / Cn) * Cn;
                outf[(size_t)r * Cn + c] = b3v[labelv[r] * Cn + c];
            }
        }
        return;
    }

    // XCD-aware bijective block swizzle (NGEMM % 8 == 0)
    const int gx = (bx & 7) * (NGEMM / 8) + (bx >> 3);
    const int rt = gx % NTRk;
    const int col0 = (gx / NTRk) * TN;

    int expert = -1, row0 = 0, rowmax = 0, acc_t = 0;
    int prev = meta[0];
    #pragma unroll
    for (int e = 0; e < En; e++) {
        int nxt = meta[e + 1];
        int c = nxt - prev;
        int t = (c + TM - 1) / TM;
        if (expert < 0 && rt < acc_t + t) {
            expert = e; row0 = prev + (rt - acc_t) * TM; rowmax = nxt - 1;
        }
        acc_t += t; prev = nxt;
    }
    if (expert < 0) return;

    const u16* Wexp = Wt + (size_t)expert * N * K;

    const int lane = tid & 63;
    const int wid = tid >> 6;
    const int wm = (wid & 1) * (TM / 2);
    const int wn = (wid >> 1) * (TN / 2);
    const int l15 = lane & 15;
    const int lq = lane >> 4;

    // staging: slot idx -> row rl = idx>>2, slot c = idx&3 holds global
    // k-chunk c^((rl>>1)&3); LDS off = 16B * (stagebase + region + idx).
    const u16* aptr[ALOAD]; int aoff[ALOAD];
    const u16* bptr[BLOAD]; int boff[BLOAD];
    #pragma unroll
    for (int s = 0; s < ALOAD; s++) {
        int idx = tid + s * 256;
        int rl = idx >> 2, c = idx & 3;
        int kq = c ^ ((rl >> 1) & 3);
        int rg = row0 + rl; if (rg > rowmax) rg = rowmax;
        if (GATHER) rg = perm[rg];
        aptr[s] = A + (size_t)rg * K + kq * 8;
        aoff[s] = idx * 8;
    }
    #pragma unroll
    for (int s = 0; s < BLOAD; s++) {
        int idx = tid + s * 256;
        int rl = idx >> 2, c = idx & 3;
        int kq = c ^ ((rl >> 1) & 3);
        bptr[s] = Wexp + (size_t)(col0 + rl) * K + kq * 8;
        boff[s] = ASLOT * 8 + idx * 8;
    }

    constexpr int MI = TM / 32;    // 16-row fragments per wave (M)
    constexpr int NJ = TN / 32;    // 16-col fragments per wave (N)
    f32x4 acc[MI][NJ];
    #pragma unroll
    for (int i = 0; i < MI; i++)
        #pragma unroll
        for (int j = 0; j < NJ; j++) acc[i][j] = (f32x4){0.f, 0.f, 0.f, 0.f};

    // read-side swizzled chunk offset (u16): row bits 1..2 == l15 bits 1..2
    const int cp = (lq ^ ((l15 >> 1) & 3)) * 8;

    auto stage_issue = [&](int buf, int t) {
        const int base = buf * (STAGE * 8);
        const int ko = t * BK;
        #pragma unroll
        for (int s = 0; s < ALOAD; s++) g2l16(aptr[s] + ko, &SM[base + aoff[s]]);
        #pragma unroll
        for (int s = 0; s < BLOAD; s++) g2l16(bptr[s] + ko, &SM[base + boff[s]]);
    };

    auto kstep = [&](int buf) {
        const u16* As = &SM[buf * (STAGE * 8)];
        const u16* Bs = As + ASLOT * 8;
        bf16x8 af[MI], bf[NJ];
        #pragma unroll
        for (int i = 0; i < MI; i++)
            af[i] = *(const bf16x8*)&As[(wm + i * 16 + l15) * BK + cp];
        #pragma unroll
        for (int j = 0; j < NJ; j++)
            bf[j] = *(const bf16x8*)&Bs[(wn + j * 16 + l15) * BK + cp];
        #pragma unroll
        for (int i = 0; i < MI; i++)
            #pragma unroll
            for (int j = 0; j < NJ; j++)
                acc[i][j] = __builtin_amdgcn_mfma_f32_16x16x32_bf16(
                    af[i], bf[j], acc[i][j], 0, 0, 0);
    };

    // prologue: stage 0 and stage 1 (ordered groups for exact vmcnt counting)
    stage_issue(0, 0);
    asm volatile("" ::: "memory");
    stage_issue(1, 1);
    asm volatile("" ::: "memory");

    int rb = 0;   // buffer read this iteration
    for (int t = 0; t < T - 1; t++) {
        // wait: all but the newest LW loads done -> stage t fully in LDS
        if constexpr (LW == 2)
            asm volatile("s_waitcnt vmcnt(2) lgkmcnt(0)" ::: "memory");
        else if constexpr (LW == 3)
            asm volatile("s_waitcnt vmcnt(3) lgkmcnt(0)" ::: "memory");
        else
            asm volatile("s_waitcnt vmcnt(4) lgkmcnt(0)" ::: "memory");
        __builtin_amdgcn_s_barrier();
        asm volatile("" ::: "memory");
        if (t + 2 < T) {
            int wb = rb + 2; if (wb >= 3) wb -= 3;
            stage_issue(wb, t + 2);
        }
        asm volatile("" ::: "memory");
        kstep(rb);
        rb = (rb == 2) ? 0 : rb + 1;
    }
    // peeled last iteration: full drain
    asm volatile("s_waitcnt vmcnt(0) lgkmcnt(0)" ::: "memory");
    __builtin_amdgcn_s_barrier();
    asm volatile("" ::: "memory");
    kstep(rb);

    if (!FUSE3) {
        // bias + ELU -> global bf16.  C/D: col=l15, row=lq*4+reg
        #pragma unroll
        for (int i = 0; i < MI; i++) {
            #pragma unroll
            for (int j = 0; j < NJ; j++) {
                int col = col0 + wn + j * 16 + l15;
                float bv = bias[expert * N + col];
                #pragma unroll
                for (int r = 0; r < 4; r++) {
                    int grow = row0 + wm + i * 16 + lq * 4 + r;
                    if (grow <= rowmax) {
                        float v = acc[i][j][r] + bv;
                        v = (v > 0.f) ? v : (expf(v) - 1.f);
                        outb[(size_t)grow * N + col] = f2b(v);
                    }
                }
            }
        }
    } else {
        // fused layer 3: k-split over this block's TN h-cols
        __syncthreads();
        u16* H = &SM[0];   // [TM][HSTR] bf16
        #pragma unroll
        for (int i = 0; i < MI; i++) {
            #pragma unroll
            for (int j = 0; j < NJ; j++) {
                int col = wn + j * 16 + l15;
                float bv = bias[expert * N + col0 + col];
                #pragma unroll
                for (int r = 0; r < 4; r++) {
                    float v = acc[i][j][r] + bv;
                    v = (v > 0.f) ? v : (expf(v) - 1.f);
                    H[(wm + i * 16 + lq * 4 + r) * HSTR + col] = f2b(v);
                }
            }
        }
        __syncthreads();
        constexpr int RI = TM / 64;         // 16-row frags per wave (TM/4 rows)
        constexpr int KC = TN / 32;         // k-chunks over this block's h-cols
        const int rh = wid * (TM / 4);
        f32x4 a3[RI][3];
        #pragma unroll
        for (int ri = 0; ri < RI; ri++)
            #pragma unroll
            for (int j = 0; j < 3; j++) a3[ri][j] = (f32x4){0.f, 0.f, 0.f, 0.f};
        #pragma unroll
        for (int ki = 0; ki < KC; ki++) {
            bf16x8 ha[RI];
            #pragma unroll
            for (int ri = 0; ri < RI; ri++)
                ha[ri] = *(const bf16x8*)&H[(rh + ri * 16 + l15) * HSTR + ki * 32 + lq * 8];
            #pragma unroll
            for (int j = 0; j < 3; j++) {
                bf16x8 wb = *(const bf16x8*)
                    &Wt3[((size_t)expert * NP3 + j * 16 + l15) * H2n + col0 + ki * 32 + lq * 8];
                #pragma unroll
                for (int ri = 0; ri < RI; ri++)
                    a3[ri][j] = __builtin_amdgcn_mfma_f32_16x16x32_bf16(
                        ha[ri], wb, a3[ri][j], 0, 0, 0);
            }
        }
        #pragma unroll
        for (int j = 0; j < 3; j++) {
            int col = j * 16 + l15;
            if (col < Cn) {
                #pragma unroll
                for (int ri = 0; ri < RI; ri++) {
                    #pragma unroll
                    for (int r = 0; r < 4; r++) {
                        int grow = row0 + rh + ri * 16 + lq * 4 + r;
                        if (grow <= rowmax)
                            atomicAdd(&outf[(size_t)perm[grow] * Cn + col], a3[ri][j][r]);
                    }
                }
            }
        }
    }
}

// ---------------------------------------------------------------------------
extern "C" void kernel_launch(void* const* d_in, const int* in_sizes, int n_in,
                              void* d_out, int out_size, void* d_ws, size_t ws_size,
                              hipStream_t stream)
{
    const float* xs = (const float*)d_in[0];
    const float* xp = (const float*)d_in[1];
    const float* W1 = (const float*)d_in[2];
    const float* b1 = (const float*)d_in[3];
    const float* W2 = (const float*)d_in[4];
    const float* b2 = (const float*)d_in[5];
    const float* W3 = (const float*)d_in[6];
    const float* b3 = (const float*)d_in[7];
    const int* label = (const int*)d_in[8];
    float* out = (float*)d_out;

    char* ws = (char*)d_ws;
    int* meta = (int*)ws;                                    // 64 B
    int* perm = (int*)(ws + 64);                             // 16 KB
    u16* Xb  = (u16*)(ws + (64 << 10));                      // 8 MB [4096][1024] (orig)
    u16* W1t = (u16*)(ws + (64 << 10) + (8  << 20));         // 16 MB [8][1024][1024]
    u16* W2t = (u16*)(ws + (64 << 10) + (24 << 20));         // 8 MB  [8][512][1024]
    u16* h1b = (u16*)(ws + (64 << 10) + (32 << 20));         // 8 MB  [4096][1024] (sorted)
    u16* W3t = (u16*)(ws + (64 << 10) + (40 << 20));         // 393 KB [8][48][512]

    prep1_kernel<<<P1_TOT, 256, 0, stream>>>(
        xs, xp, W1, label, meta, perm, Xb, W1t);

    // L1 GEMM: 128x64 tiles -> (4096/128+8)*16 = 640 blocks + 1216 prep2 jobs
    mfma_gemm<K1n, H1n, 128, 64, true, false, true><<<640 + 1216, 256, 0, stream>>>(
        Xb, W1t, b1, meta, perm, h1b, nullptr, out,
        W2, W3, b3, label, W2t, W3t);

    // L2 + fused L3: 64x64 tiles -> (4096/64+8)*8 = 576 blocks
    mfma_gemm<H1n, H2n, 64, 64, false, true, false><<<576, 256, 0, stream>>>(
        h1b, W2t, b2, meta, perm, nullptr, W3t, out,
        nullptr, nullptr, nullptr, nullptr, nullptr, nullptr);
}